// Round 2
// baseline (813.739 us; speedup 1.0000x reference)
//
#include <hip/hip_runtime.h>
#include <hip/hip_bf16.h>

#define EMB 384
#define NPOS 8193   // 2L+1 state positions
#define LAYERS 12
#define BATCH 4
#define PT 32           // positions per workgroup
#define LDSROW 392      // 384 + 8 pad (bf16 elems) -> 784B row stride, 2-way bank alias only
#define X1OFF (34 * LDSROW)

typedef __attribute__((ext_vector_type(8))) short bf16x8;
typedef __attribute__((ext_vector_type(4))) float f32x4;

__device__ __forceinline__ float b2f(unsigned short u) {
    union { unsigned int i; float f; } v; v.i = ((unsigned int)u) << 16; return v.f;
}
__device__ __forceinline__ unsigned short f2b(float f) {
    union { float f; unsigned int i; } v; v.f = f;
    unsigned int x = v.i;
    return (unsigned short)((x + 0x7FFFu + ((x >> 16) & 1u)) >> 16);
}

// ---- weight pre-swizzle: W_swz[layer][kb(36)][nb(24)][lane(64)][8 bf16]
// logical K: 0..383 = w_center, 384..767 = w_right, 768..1151 = w_left
// per 16x32 block: lane holds col n = nb*16 + (lane&15), k = kb*32 + 8*(lane>>4) + e
__global__ void w_prep(const float* __restrict__ wl, const float* __restrict__ wc,
                       const float* __restrict__ wr, unsigned short* __restrict__ wswz) {
    int idx = blockIdx.x * blockDim.x + threadIdx.x;
    const int total = LAYERS * 36 * 24 * 64;
    if (idx >= total) return;
    int lane = idx & 63;
    int t = idx >> 6;
    int nb = t % 24; t /= 24;
    int kb = t % 36; t /= 36;
    int layer = t;
    int seg = kb / 12;
    const float* src = (seg == 0 ? wc : (seg == 1 ? wr : wl)) + (size_t)layer * EMB * EMB;
    int kloc = (kb % 12) * 32 + ((lane >> 4) << 3);
    int n = nb * 16 + (lane & 15);
    unsigned short o[8];
#pragma unroll
    for (int e = 0; e < 8; ++e) o[e] = f2b(src[(size_t)n * EMB + kloc + e]);
    *reinterpret_cast<uint4*>(wswz + (size_t)idx * 8) = *reinterpret_cast<uint4*>(o);
}

// ---- initial state X[b][pos][plane][384] bf16
__global__ void x_init(const float* __restrict__ embs, const float* __restrict__ mask,
                       unsigned short* __restrict__ X) {
    int idx = blockIdx.x * blockDim.x + threadIdx.x;
    const int total = BATCH * NPOS * (EMB / 8);
    if (idx >= total) return;
    int dg = idx % (EMB / 8);
    int t = idx / (EMB / 8);
    int pos = t % NPOS;
    int b = t / NPOS;
    int d0 = dg * 8;
    const float* m = mask + (size_t)b * EMB + d0;
    const float* p0src;
    if (pos >= 1 && pos <= 4096) p0src = embs + ((size_t)b * 4096 + (pos - 1)) * EMB + d0;
    else if (pos == 8192)        p0src = embs + (size_t)b * 4096 * EMB + d0;
    else                         p0src = m;
    unsigned short o0[8], o1[8];
#pragma unroll
    for (int e = 0; e < 8; ++e) { o0[e] = f2b(p0src[e]); o1[e] = f2b(m[e]); }
    size_t base = ((size_t)b * NPOS + pos) * 2 * EMB + d0;
    *reinterpret_cast<uint4*>(X + base)       = *reinterpret_cast<uint4*>(o0);
    *reinterpret_cast<uint4*>(X + base + EMB) = *reinterpret_cast<uint4*>(o1);
}

// ---- one layer: y[j] = relu(Wc x[j+1] + Wr x0[j+2] + Wl x0[j] + b) + x[j+1], then scramble-scatter
__global__ __launch_bounds__(256, 2) void layer_k(
    const unsigned short* __restrict__ Xin, unsigned short* __restrict__ Xout,
    const unsigned short* __restrict__ W, const float* __restrict__ bias) {
    __shared__ unsigned short lds[(34 + 32) * LDSROW];
    const int tid = threadIdx.x;
    const int b = blockIdx.y;
    const int j0 = blockIdx.x * PT;
    const size_t xbase = (size_t)b * NPOS * 2 * EMB;

    // stage X tile: rows 0..33 = plane0 pos j0..j0+33 (clamped), rows 34..65 = plane1 pos j0+1..j0+32
    for (int idx = tid; idx < 66 * 48; idx += 256) {
        int row = idx / 48, cg = idx % 48;
        int pos, plane, ldsoff;
        if (row < 34) { pos = j0 + row; if (pos > 8192) pos = 8192; plane = 0; ldsoff = row * LDSROW; }
        else          { pos = j0 + 1 + (row - 34); plane = 1; ldsoff = X1OFF + (row - 34) * LDSROW; }
        const uint4* src = reinterpret_cast<const uint4*>(Xin + xbase + ((size_t)pos * 2 + plane) * EMB + cg * 8);
        *reinterpret_cast<uint4*>(&lds[ldsoff + cg * 8]) = *src;
    }
    __syncthreads();

    const int lane = tid & 63;
    const int w = tid >> 6;              // 0..3, wave's 96-col slice
    const int lrow = lane & 15;
    const int coff = (lane >> 4) << 3;   // 0,8,16,24
    const int nbase = w * 96;

    float biasv[6];
#pragma unroll
    for (int n = 0; n < 6; ++n) biasv[n] = bias[nbase + n * 16 + lrow];

    // A-fragment LDS row bases per mblk (rows 0..31 = plane0, 32..63 = plane1)
    int bc[4], br[4], bl[4];
#pragma unroll
    for (int m = 0; m < 4; ++m) {
        int p = ((m & 1) << 4) + lrow;                 // position offset in tile
        bc[m] = (m < 2) ? ((p + 1) * LDSROW) : (X1OFF + p * LDSROW);
        br[m] = (p + 2) * LDSROW;
        bl[m] = p * LDSROW;
    }

    f32x4 acc[4][6];
#pragma unroll
    for (int m = 0; m < 4; ++m)
#pragma unroll
        for (int n = 0; n < 6; ++n) acc[m][n] = f32x4{0.f, 0.f, 0.f, 0.f};

    const bf16x8* Wv = reinterpret_cast<const bf16x8*>(W);

#define KSEG(SEGI, BASEARR)                                                          \
    for (int kc = 0; kc < 12; ++kc) {                                                \
        const int kb = SEGI * 12 + kc;                                               \
        const bf16x8* wb = Wv + ((size_t)kb * 24 + w * 6) * 64 + lane;               \
        bf16x8 bfr[6];                                                               \
        _Pragma("unroll")                                                            \
        for (int n = 0; n < 6; ++n) bfr[n] = wb[n * 64];                             \
        const int c = kc * 32 + coff;                                                \
        _Pragma("unroll")                                                            \
        for (int m = 0; m < 4; ++m) {                                                \
            bf16x8 afr = *reinterpret_cast<const bf16x8*>(&lds[BASEARR[m] + c]);     \
            _Pragma("unroll")                                                        \
            for (int n = 0; n < 6; ++n)                                              \
                acc[m][n] = __builtin_amdgcn_mfma_f32_16x16x32_bf16(afr, bfr[n],     \
                                                                    acc[m][n], 0, 0, 0); \
        }                                                                            \
    }
    KSEG(0, bc)
    KSEG(1, br)
    KSEG(2, bl)
#undef KSEG

    // epilogue: bias + relu + residual (reads LDS X tile) into acc
#pragma unroll
    for (int m = 0; m < 4; ++m) {
#pragma unroll
        for (int ri = 0; ri < 4; ++ri) {
            int r = m * 16 + ((lane >> 4) << 2) + ri;   // output row 0..63
            int p = r & 31;
#pragma unroll
            for (int n = 0; n < 6; ++n) {
                int col = nbase + n * 16 + lrow;
                int ca = (r < 32) ? ((p + 1) * LDSROW + col) : (X1OFF + p * LDSROW + col);
                float v = acc[m][n][ri] + biasv[n];
                v = fmaxf(v, 0.f) + b2f(lds[ca]);
                acc[m][n][ri] = v;
            }
        }
    }
    __syncthreads();
    // write bf16 out-tile to LDS [64][LDSROW]
#pragma unroll
    for (int m = 0; m < 4; ++m)
#pragma unroll
        for (int ri = 0; ri < 4; ++ri) {
            int r = m * 16 + ((lane >> 4) << 2) + ri;
#pragma unroll
            for (int n = 0; n < 6; ++n) {
                int col = nbase + n * 16 + lrow;
                lds[r * LDSROW + col] = f2b(acc[m][n][ri]);
            }
        }
    __syncthreads();
    // coalesced scatter to Xout with scramble permutation
    for (int idx = tid; idx < 64 * 48; idx += 256) {
        int r = idx / 48, cg = idx % 48;
        int plane = r >> 5, p = r & 31;
        int j = j0 + p;
        if (j > 8190) continue;
        int pt = (j & 1) ? ((j + NPOS) >> 1) : ((j >> 1) + 1);
        uint4 val = *reinterpret_cast<uint4*>(&lds[r * LDSROW + cg * 8]);
        *reinterpret_cast<uint4*>(Xout + xbase + ((size_t)pt * 2 + plane) * EMB + cg * 8) = val;
        if (j == 0)
            *reinterpret_cast<uint4*>(Xout + xbase + ((size_t)8192 * 2 + plane) * EMB + cg * 8) = val;
        if (j == 8189)
            *reinterpret_cast<uint4*>(Xout + xbase + ((size_t)plane) * EMB + cg * 8) = val;
    }
}

// ---- finalize: the reference applies a 13th scramble_and_pad(x[:,1:-1]) then takes
// positions 1..4096. Composed: out[j] = scan-buffer position (2j+1).
// out0 = X[b][2j+1][0][:], out1 = X[b][2j+1][1][:], f32
__global__ void finalize(const unsigned short* __restrict__ X, float* __restrict__ out) {
    int idx = blockIdx.x * blockDim.x + threadIdx.x;
    const int total = BATCH * 4096 * 48;
    if (idx >= total) return;
    int dg = idx % 48; int t = idx / 48;
    int j = t % 4096; int b = t / 4096;
    int d0 = dg * 8;
    size_t src0 = ((size_t)b * NPOS + (2 * j + 1)) * 2 * EMB + d0;
    size_t o0 = ((size_t)b * 4096 + j) * EMB + d0;
    size_t o1 = o0 + (size_t)BATCH * 4096 * EMB;
    float v0[8], v1[8];
#pragma unroll
    for (int e = 0; e < 8; ++e) { v0[e] = b2f(X[src0 + e]); v1[e] = b2f(X[src0 + EMB + e]); }
    *reinterpret_cast<float4*>(out + o0)     = *reinterpret_cast<float4*>(&v0[0]);
    *reinterpret_cast<float4*>(out + o0 + 4) = *reinterpret_cast<float4*>(&v0[4]);
    *reinterpret_cast<float4*>(out + o1)     = *reinterpret_cast<float4*>(&v1[0]);
    *reinterpret_cast<float4*>(out + o1 + 4) = *reinterpret_cast<float4*>(&v1[4]);
}

extern "C" void kernel_launch(void* const* d_in, const int* in_sizes, int n_in,
                              void* d_out, int out_size, void* d_ws, size_t ws_size,
                              hipStream_t stream) {
    const float* embs = (const float*)d_in[0];
    const float* mask = (const float*)d_in[1];
    const float* wl   = (const float*)d_in[2];
    const float* wc   = (const float*)d_in[3];
    const float* wr   = (const float*)d_in[4];
    const float* bias = (const float*)d_in[5];

    const size_t XELEMS = (size_t)BATCH * NPOS * 2 * EMB;    // 25,168,896
    unsigned short* X0 = (unsigned short*)d_ws;
    unsigned short* X1 = X0 + XELEMS;
    unsigned short* W  = X1 + XELEMS;                         // 12*36*24*64*8 elems

    {
        int total = LAYERS * 36 * 24 * 64;
        w_prep<<<(total + 255) / 256, 256, 0, stream>>>(wl, wc, wr, W);
    }
    {
        int total = BATCH * NPOS * (EMB / 8);
        x_init<<<(total + 255) / 256, 256, 0, stream>>>(embs, mask, X0);
    }
    unsigned short* bufs[2] = { X0, X1 };
    for (int l = 0; l < LAYERS; ++l) {
        layer_k<<<dim3(256, BATCH), 256, 0, stream>>>(
            bufs[l & 1], bufs[(l + 1) & 1],
            W + (size_t)l * 36 * 24 * 64 * 8, bias + (size_t)l * EMB);
    }
    {
        int total = BATCH * 4096 * 48;
        finalize<<<(total + 255) / 256, 256, 0, stream>>>(bufs[0], (float*)d_out);
    }
}

// Round 3
// 672.325 us; speedup vs baseline: 1.2103x; 1.2103x over previous
//
#include <hip/hip_runtime.h>
#include <hip/hip_bf16.h>

#define EMB 384
#define NPOS 8193   // 2L+1 state positions
#define LAYERS 12
#define BATCH 4
#define PT 32           // positions per workgroup
#define LDSROW 392      // 384 + 8 pad (bf16 elems) -> 784B row stride, 2-way bank alias only
#define X1OFF (34 * LDSROW)

typedef __attribute__((ext_vector_type(8))) short bf16x8;
typedef __attribute__((ext_vector_type(4))) float f32x4;

__device__ __forceinline__ float b2f(unsigned short u) {
    union { unsigned int i; float f; } v; v.i = ((unsigned int)u) << 16; return v.f;
}
__device__ __forceinline__ unsigned short f2b(float f) {
    union { float f; unsigned int i; } v; v.f = f;
    unsigned int x = v.i;
    return (unsigned short)((x + 0x7FFFu + ((x >> 16) & 1u)) >> 16);
}

// ---- weight pre-swizzle: W_swz[layer][kb(36)][nb(24)][lane(64)][8 bf16]
// logical K: 0..383 = w_center, 384..767 = w_right, 768..1151 = w_left
// per 16x32 block: lane holds col n = nb*16 + (lane&15), k = kb*32 + 8*(lane>>4) + e
__global__ void w_prep(const float* __restrict__ wl, const float* __restrict__ wc,
                       const float* __restrict__ wr, unsigned short* __restrict__ wswz) {
    int idx = blockIdx.x * blockDim.x + threadIdx.x;
    const int total = LAYERS * 36 * 24 * 64;
    if (idx >= total) return;
    int lane = idx & 63;
    int t = idx >> 6;
    int nb = t % 24; t /= 24;
    int kb = t % 36; t /= 36;
    int layer = t;
    int seg = kb / 12;
    const float* src = (seg == 0 ? wc : (seg == 1 ? wr : wl)) + (size_t)layer * EMB * EMB;
    int kloc = (kb % 12) * 32 + ((lane >> 4) << 3);
    int n = nb * 16 + (lane & 15);
    unsigned short o[8];
#pragma unroll
    for (int e = 0; e < 8; ++e) o[e] = f2b(src[(size_t)n * EMB + kloc + e]);
    *reinterpret_cast<uint4*>(wswz + (size_t)idx * 8) = *reinterpret_cast<uint4*>(o);
}

// ---- initial state X[b][pos][plane][384] bf16
__global__ void x_init(const float* __restrict__ embs, const float* __restrict__ mask,
                       unsigned short* __restrict__ X) {
    int idx = blockIdx.x * blockDim.x + threadIdx.x;
    const int total = BATCH * NPOS * (EMB / 8);
    if (idx >= total) return;
    int dg = idx % (EMB / 8);
    int t = idx / (EMB / 8);
    int pos = t % NPOS;
    int b = t / NPOS;
    int d0 = dg * 8;
    const float* m = mask + (size_t)b * EMB + d0;
    const float* p0src;
    if (pos >= 1 && pos <= 4096) p0src = embs + ((size_t)b * 4096 + (pos - 1)) * EMB + d0;
    else if (pos == 8192)        p0src = embs + (size_t)b * 4096 * EMB + d0;
    else                         p0src = m;
    unsigned short o0[8], o1[8];
#pragma unroll
    for (int e = 0; e < 8; ++e) { o0[e] = f2b(p0src[e]); o1[e] = f2b(m[e]); }
    size_t base = ((size_t)b * NPOS + pos) * 2 * EMB + d0;
    *reinterpret_cast<uint4*>(X + base)       = *reinterpret_cast<uint4*>(o0);
    *reinterpret_cast<uint4*>(X + base + EMB) = *reinterpret_cast<uint4*>(o1);
}

// ---- one layer: y[j,pl] = relu(Wc x[j+1,pl] + Wr x0[j+2] + Wl x0[j] + b) + x[j+1,pl]
// Neighbor term is plane-independent: computed once (m=0,1), copied to plane1 accs.
// 8 waves x 48 output cols each; W double-buffered in regs.
__global__ __launch_bounds__(512, 4) void layer_k(
    const unsigned short* __restrict__ Xin, unsigned short* __restrict__ Xout,
    const unsigned short* __restrict__ W, const float* __restrict__ bias) {
    __shared__ unsigned short lds[(34 + 32) * LDSROW];
    const int tid = threadIdx.x;
    const int b = blockIdx.y;
    const int j0 = blockIdx.x * PT;
    const size_t xbase = (size_t)b * NPOS * 2 * EMB;

    // stage X tile: rows 0..33 = plane0 pos j0..j0+33 (clamped), rows 34..65 = plane1 pos j0+1..j0+32
    for (int idx = tid; idx < 66 * 48; idx += 512) {
        int row = idx / 48, cg = idx % 48;
        int pos, plane, ldsoff;
        if (row < 34) { pos = j0 + row; if (pos > 8192) pos = 8192; plane = 0; ldsoff = row * LDSROW; }
        else          { pos = j0 + 1 + (row - 34); plane = 1; ldsoff = X1OFF + (row - 34) * LDSROW; }
        const uint4* src = reinterpret_cast<const uint4*>(Xin + xbase + ((size_t)pos * 2 + plane) * EMB + cg * 8);
        *reinterpret_cast<uint4*>(&lds[ldsoff + cg * 8]) = *src;
    }
    __syncthreads();

    const int lane = tid & 63;
    const int w = tid >> 6;              // 0..7, wave's 48-col slice
    const int lrow = lane & 15;
    const int coff = (lane >> 4) << 3;   // 0,8,16,24

    // A-fragment LDS row bases (rows 0..31 out = plane0, 32..63 = plane1)
    int bc[4], br2[2], bl2[2];
#pragma unroll
    for (int m = 0; m < 4; ++m) {
        int p = ((m & 1) << 4) + lrow;
        bc[m] = (m < 2) ? ((p + 1) * LDSROW) : (X1OFF + p * LDSROW);
    }
#pragma unroll
    for (int m = 0; m < 2; ++m) {
        int p = (m << 4) + lrow;
        br2[m] = (p + 2) * LDSROW;
        bl2[m] = p * LDSROW;
    }

    f32x4 acc[4][3];
#pragma unroll
    for (int m = 0; m < 2; ++m)
#pragma unroll
        for (int n = 0; n < 3; ++n) acc[m][n] = f32x4{0.f, 0.f, 0.f, 0.f};

    const bf16x8* Wv = reinterpret_cast<const bf16x8*>(W);
    const bf16x8* wb = Wv + (size_t)(w * 3) * 64 + lane;   // fragment(kb,n) = wb[(kb*24+n)*64]

    bf16x8 wcur[3], wnxt[3];
#pragma unroll
    for (int n = 0; n < 3; ++n) wcur[n] = wb[(12 * 24 + n) * 64];   // kb=12 (first neighbor)

    // ---- neighbor phase: kb 12..23 = right (x0[p+2]), kb 24..35 = left (x0[p]), m=0,1 only
#pragma unroll
    for (int kb = 12; kb < 36; ++kb) {
        const int nkb = (kb == 35) ? 0 : kb + 1;    // after neighbors, chain into center kb=0
#pragma unroll
        for (int n = 0; n < 3; ++n) wnxt[n] = wb[(nkb * 24 + n) * 64];
        const int* B = (kb < 24) ? br2 : bl2;
        const int c = (kb % 12) * 32 + coff;
#pragma unroll
        for (int m = 0; m < 2; ++m) {
            bf16x8 afr = *reinterpret_cast<const bf16x8*>(&lds[B[m] + c]);
#pragma unroll
            for (int n = 0; n < 3; ++n)
                acc[m][n] = __builtin_amdgcn_mfma_f32_16x16x32_bf16(afr, wcur[n], acc[m][n], 0, 0, 0);
        }
#pragma unroll
        for (int n = 0; n < 3; ++n) wcur[n] = wnxt[n];
    }
    // copy plane-independent neighbor result to plane1 accumulators
#pragma unroll
    for (int m = 0; m < 2; ++m)
#pragma unroll
        for (int n = 0; n < 3; ++n) acc[m + 2][n] = acc[m][n];

    // ---- center phase: kb 0..11, all 4 m-blocks
#pragma unroll
    for (int kb = 0; kb < 12; ++kb) {
        if (kb < 11) {
#pragma unroll
            for (int n = 0; n < 3; ++n) wnxt[n] = wb[((kb + 1) * 24 + n) * 64];
        }
        const int c = kb * 32 + coff;
#pragma unroll
        for (int m = 0; m < 4; ++m) {
            bf16x8 afr = *reinterpret_cast<const bf16x8*>(&lds[bc[m] + c]);
#pragma unroll
            for (int n = 0; n < 3; ++n)
                acc[m][n] = __builtin_amdgcn_mfma_f32_16x16x32_bf16(afr, wcur[n], acc[m][n], 0, 0, 0);
        }
#pragma unroll
        for (int n = 0; n < 3; ++n) wcur[n] = wnxt[n];
    }

    float biasv[3];
#pragma unroll
    for (int n = 0; n < 3; ++n) biasv[n] = bias[w * 48 + n * 16 + lrow];

    // epilogue: bias + relu + residual (reads LDS X tile) into acc
#pragma unroll
    for (int m = 0; m < 4; ++m) {
#pragma unroll
        for (int ri = 0; ri < 4; ++ri) {
            int r = m * 16 + ((lane >> 4) << 2) + ri;   // output row 0..63
            int p = r & 31;
#pragma unroll
            for (int n = 0; n < 3; ++n) {
                int col = w * 48 + n * 16 + lrow;
                int ca = (r < 32) ? ((p + 1) * LDSROW + col) : (X1OFF + p * LDSROW + col);
                float v = acc[m][n][ri] + biasv[n];
                v = fmaxf(v, 0.f) + b2f(lds[ca]);
                acc[m][n][ri] = v;
            }
        }
    }
    __syncthreads();
    // write bf16 out-tile to LDS [64][LDSROW]
#pragma unroll
    for (int m = 0; m < 4; ++m)
#pragma unroll
        for (int ri = 0; ri < 4; ++ri) {
            int r = m * 16 + ((lane >> 4) << 2) + ri;
#pragma unroll
            for (int n = 0; n < 3; ++n) {
                int col = w * 48 + n * 16 + lrow;
                lds[r * LDSROW + col] = f2b(acc[m][n][ri]);
            }
        }
    __syncthreads();
    // coalesced scatter to Xout with scramble permutation
    for (int idx = tid; idx < 64 * 48; idx += 512) {
        int r = idx / 48, cg = idx % 48;
        int plane = r >> 5, p = r & 31;
        int j = j0 + p;
        if (j > 8190) continue;
        int pt = (j & 1) ? ((j + NPOS) >> 1) : ((j >> 1) + 1);
        uint4 val = *reinterpret_cast<uint4*>(&lds[r * LDSROW + cg * 8]);
        *reinterpret_cast<uint4*>(Xout + xbase + ((size_t)pt * 2 + plane) * EMB + cg * 8) = val;
        if (j == 0)
            *reinterpret_cast<uint4*>(Xout + xbase + ((size_t)8192 * 2 + plane) * EMB + cg * 8) = val;
        if (j == 8189)
            *reinterpret_cast<uint4*>(Xout + xbase + ((size_t)plane) * EMB + cg * 8) = val;
    }
}

// ---- finalize: 13th scramble composed with slice -> out[j] = scan-buffer position (2j+1)
__global__ void finalize(const unsigned short* __restrict__ X, float* __restrict__ out) {
    int idx = blockIdx.x * blockDim.x + threadIdx.x;
    const int total = BATCH * 4096 * 48;
    if (idx >= total) return;
    int dg = idx % 48; int t = idx / 48;
    int j = t % 4096; int b = t / 4096;
    int d0 = dg * 8;
    size_t src0 = ((size_t)b * NPOS + (2 * j + 1)) * 2 * EMB + d0;
    size_t o0 = ((size_t)b * 4096 + j) * EMB + d0;
    size_t o1 = o0 + (size_t)BATCH * 4096 * EMB;
    float v0[8], v1[8];
#pragma unroll
    for (int e = 0; e < 8; ++e) { v0[e] = b2f(X[src0 + e]); v1[e] = b2f(X[src0 + EMB + e]); }
    *reinterpret_cast<float4*>(out + o0)     = *reinterpret_cast<float4*>(&v0[0]);
    *reinterpret_cast<float4*>(out + o0 + 4) = *reinterpret_cast<float4*>(&v0[4]);
    *reinterpret_cast<float4*>(out + o1)     = *reinterpret_cast<float4*>(&v1[0]);
    *reinterpret_cast<float4*>(out + o1 + 4) = *reinterpret_cast<float4*>(&v1[4]);
}

extern "C" void kernel_launch(void* const* d_in, const int* in_sizes, int n_in,
                              void* d_out, int out_size, void* d_ws, size_t ws_size,
                              hipStream_t stream) {
    const float* embs = (const float*)d_in[0];
    const float* mask = (const float*)d_in[1];
    const float* wl   = (const float*)d_in[2];
    const float* wc   = (const float*)d_in[3];
    const float* wr   = (const float*)d_in[4];
    const float* bias = (const float*)d_in[5];

    const size_t XELEMS = (size_t)BATCH * NPOS * 2 * EMB;    // 25,168,896
    unsigned short* X0 = (unsigned short*)d_ws;
    unsigned short* X1 = X0 + XELEMS;
    unsigned short* W  = X1 + XELEMS;                         // 12*36*24*64*8 elems

    {
        int total = LAYERS * 36 * 24 * 64;
        w_prep<<<(total + 255) / 256, 256, 0, stream>>>(wl, wc, wr, W);
    }
    {
        int total = BATCH * NPOS * (EMB / 8);
        x_init<<<(total + 255) / 256, 256, 0, stream>>>(embs, mask, X0);
    }
    unsigned short* bufs[2] = { X0, X1 };
    for (int l = 0; l < LAYERS; ++l) {
        layer_k<<<dim3(256, BATCH), 512, 0, stream>>>(
            bufs[l & 1], bufs[(l + 1) & 1],
            W + (size_t)l * 36 * 24 * 64 * 8, bias + (size_t)l * EMB);
    }
    {
        int total = BATCH * 4096 * 48;
        finalize<<<(total + 255) / 256, 256, 0, stream>>>(bufs[0], (float*)d_out);
    }
}